// Round 9
// baseline (66.636 us; speedup 1.0000x reference)
//
#include <hip/hip_runtime.h>
#include <hip/hip_bf16.h>

#define TOKENS 16384
#define NEXP 8
#define INF 512
#define OUTF 512

#define WM 64              // M rows per wave-block
#define WN 64              // N cols per wave-block
#define KSTEP 32
#define NST (INF / KSTEP)  // 16 K-steps
#define MT 40              // 64-row tiles/expert: covers cnt<=2560 (+12 sigma)
#define EROWS 5120         // perm region stride (unchanged layout)

using f32x4 = __attribute__((ext_vector_type(4))) float;
using bfrag = __attribute__((ext_vector_type(8))) __bf16;
using s8v   = __attribute__((ext_vector_type(8))) short;

// fp32 -> bf16 RNE
__device__ __forceinline__ short f2bf(float f) {
  union { float f; unsigned u; } v; v.f = f;
  unsigned r = v.u + 0x7fffu + ((v.u >> 16) & 1u);
  return (short)(r >> 16);
}

__device__ __forceinline__ s8v pack8(float4 a, float4 b) {
  s8v p;
  p[0] = f2bf(a.x); p[1] = f2bf(a.y); p[2] = f2bf(a.z); p[3] = f2bf(a.w);
  p[4] = f2bf(b.x); p[5] = f2bf(b.y); p[6] = f2bf(b.z); p[7] = f2bf(b.w);
  return p;
}

__device__ __forceinline__ bfrag cvt8(f32x4 lo, f32x4 hi) {
  bfrag r;
  r[0] = (__bf16)lo[0]; r[1] = (__bf16)lo[1];
  r[2] = (__bf16)lo[2]; r[3] = (__bf16)lo[3];
  r[4] = (__bf16)hi[0]; r[5] = (__bf16)hi[1];
  r[6] = (__bf16)hi[2]; r[7] = (__bf16)hi[3];
  return r;
}

__global__ void k_zero(int* __restrict__ cursor) {
  if (threadIdx.x < NEXP) cursor[threadIdx.x] = 0;
}

// Fused: blocks 0..63 scatter tokens by expert; blocks 64..1087 convert
// weight fp32 -> bf16 (contiguous [E][O][I]).
__global__ void k_prep(const int* __restrict__ gate, int* __restrict__ cursor,
                       int* __restrict__ perm, const float* __restrict__ w,
                       s8v* __restrict__ wb) {
  __shared__ int lc[NEXP], lb[NEXP];
  const int bid = blockIdx.x, tid = threadIdx.x;
  if (bid < 64) {
    if (tid < NEXP) lc[tid] = 0;
    __syncthreads();
    int t = bid * 256 + tid;
    int e = gate[t];
    int ls = atomicAdd(&lc[e], 1);
    __syncthreads();
    if (tid < NEXP) lb[tid] = lc[tid] ? atomicAdd(&cursor[tid], lc[tid]) : 0;
    __syncthreads();
    perm[e * EROWS + lb[e] + ls] = t;
  } else {
    int idx = (bid - 64) * 256 + tid;
    const float4* src = (const float4*)w + (size_t)idx * 2;
    wb[idx] = pack8(src[0], src[1]);
  }
}

// Wave-autonomous grouped GEMM: one 64-thread block = one wave = one 64x64
// output tile. A (gathered fp32 token rows) and B (bf16 weight) fragments are
// loaded straight from global into registers; fp32->bf16 cvt in-reg; register
// double-buffer over a fully-unrolled 16-step K-loop. NO LDS data, NO
// barriers, NO manual waitcnt -- per-wave compiler-inserted waits only.
// bid = e + 8*(nt + 8*mt): e -> XCD (B panel L2-local); the 8 nt-siblings of
// an A-slice are 8 bids apart (temporally adjacent -> A L2 reuse).
__global__ __launch_bounds__(64, 2)
void moe_gemm5(const float* __restrict__ inp, const short* __restrict__ wbf,
               const int* __restrict__ cursor, const int* __restrict__ perm,
               float* __restrict__ out) {
  const int bid = blockIdx.x;
  const int e  = bid & 7;
  const int r  = bid >> 3;
  const int nt = r & 7;
  const int mt = r >> 3;
  const int cnt = cursor[e];
  if (mt * WM >= cnt) return;
  const int m_valid = min(WM, cnt - mt * WM);
  const int* pb = perm + e * EROWS + mt * WM;

  const int lane = threadIdx.x;       // 0..63
  const int lr = lane & 15;
  const int lg = lane >> 4;

  // Per-lane fragment base addresses (verified frag mapping: lane(lg,lr)
  // holds row = frag*16+lr, k = lg*8 .. lg*8+7 within each 32-wide K-chunk).
  const float* aaddr[4];
#pragma unroll
  for (int i = 0; i < 4; i++) {
    int row = i * 16 + lr;
    int tok = pb[row < m_valid ? row : m_valid - 1];
    aaddr[i] = inp + (size_t)tok * INF + lg * 8;
  }
  const short* wb = wbf + ((size_t)e * OUTF + (size_t)nt * WN) * INF;
  const short* baddr[4];
#pragma unroll
  for (int j = 0; j < 4; j++)
    baddr[j] = wb + (size_t)(j * 16 + lr) * INF + lg * 8;

  f32x4 acc[4][4];
#pragma unroll
  for (int i = 0; i < 4; i++)
#pragma unroll
    for (int j = 0; j < 4; j++) acc[i][j] = (f32x4)0.0f;

  f32x4 Ar[2][4][2];
  bfrag Br[2][4];

  // prologue: stage t=0 into buffer 0
#pragma unroll
  for (int i = 0; i < 4; i++) {
    Ar[0][i][0] = *(const f32x4*)(aaddr[i]);
    Ar[0][i][1] = *(const f32x4*)(aaddr[i] + 4);
  }
#pragma unroll
  for (int j = 0; j < 4; j++) Br[0][j] = *(const bfrag*)(baddr[j]);

#pragma unroll
  for (int t = 0; t < NST; t++) {         // fully unrolled -> static indexing
    const int cur = t & 1, nxt = cur ^ 1;
    if (t + 1 < NST) {                    // prefetch t+1 (rides over MFMAs)
#pragma unroll
      for (int i = 0; i < 4; i++) {
        Ar[nxt][i][0] = *(const f32x4*)(aaddr[i] + (t + 1) * KSTEP);
        Ar[nxt][i][1] = *(const f32x4*)(aaddr[i] + (t + 1) * KSTEP + 4);
      }
#pragma unroll
      for (int j = 0; j < 4; j++)
        Br[nxt][j] = *(const bfrag*)(baddr[j] + (t + 1) * KSTEP);
    }
    bfrag af[4];
#pragma unroll
    for (int i = 0; i < 4; i++) af[i] = cvt8(Ar[cur][i][0], Ar[cur][i][1]);
#pragma unroll
    for (int i = 0; i < 4; i++)
#pragma unroll
      for (int j = 0; j < 4; j++)
        acc[i][j] = __builtin_amdgcn_mfma_f32_16x16x32_bf16(af[i], Br[cur][j],
                                                            acc[i][j], 0, 0, 0);
  }

  // epilogue: C/D col=lane&15, row=(lane>>4)*4+reg (verified mapping).
  // Store rows i*16 + lg*4 + rr; clamped-dup A rows are masked out here.
#pragma unroll
  for (int i = 0; i < 4; i++) {
#pragma unroll
    for (int rr = 0; rr < 4; rr++) {
      int rowE = i * 16 + lg * 4 + rr;
      if (rowE < m_valid) {
        int tokE = pb[rowE];
        float* orow = out + (size_t)tokE * OUTF + (size_t)nt * WN + lr;
#pragma unroll
        for (int j = 0; j < 4; j++) orow[j * 16] = acc[i][j][rr];
      }
    }
  }
}

extern "C" void kernel_launch(void* const* d_in, const int* in_sizes, int n_in,
                              void* d_out, int out_size, void* d_ws, size_t ws_size,
                              hipStream_t stream) {
  (void)in_sizes; (void)n_in; (void)out_size; (void)ws_size;
  const float* inp    = (const float*)d_in[0];
  const int*   gate   = (const int*)d_in[1];
  const float* weight = (const float*)d_in[2];
  float* out = (float*)d_out;

  char* ws = (char*)d_ws;
  int*   cursor = (int*)ws;                    // 64 B
  int*   perm   = (int*)(ws + 4096);           // 8*5120*4 = 160 KB
  short* wbf    = (short*)(ws + (1 << 20));    // 4 MB bf16 weight

  k_zero<<<1, 64, 0, stream>>>(cursor);
  k_prep<<<64 + (NEXP * OUTF * INF) / (256 * 8), 256, 0, stream>>>(
      gate, cursor, perm, weight, (s8v*)wbf);
  moe_gemm5<<<NEXP * 8 * MT, 64, 0, stream>>>(inp, wbf, cursor, perm, out);
}

// Round 10
// 64.915 us; speedup vs baseline: 1.0265x; 1.0265x over previous
//
#include <hip/hip_runtime.h>
#include <hip/hip_bf16.h>

#define TOKENS 16384
#define NEXP 8
#define INF 512
#define OUTF 512

#define BM 32              // token rows per block (owned exclusively -> A read ONCE)
#define KS 32              // K per step
#define NST (INF / KS)     // 16 K-steps
#define MAXMT 80           // 2560 rows/expert; counts ~2048±42(σ) -> +12σ safe
#define EROWS (MAXMT * BM)

using f32x4 = __attribute__((ext_vector_type(4))) float;
using bfrag = __attribute__((ext_vector_type(8))) __bf16;
using s8v   = __attribute__((ext_vector_type(8))) short;

// fp32 -> bf16 RNE
__device__ __forceinline__ short f2bf(float f) {
  union { float f; unsigned u; } v; v.f = f;
  unsigned r = v.u + 0x7fffu + ((v.u >> 16) & 1u);
  return (short)(r >> 16);
}

__device__ __forceinline__ void gload16(const void* g, void* l) {
  __builtin_amdgcn_global_load_lds(
      (const __attribute__((address_space(1))) unsigned int*)g,
      (__attribute__((address_space(3))) unsigned int*)l, 16, 0, 0);
}

__device__ __forceinline__ s8v pack8(float4 a, float4 b) {
  s8v p;
  p[0] = f2bf(a.x); p[1] = f2bf(a.y); p[2] = f2bf(a.z); p[3] = f2bf(a.w);
  p[4] = f2bf(b.x); p[5] = f2bf(b.y); p[6] = f2bf(b.z); p[7] = f2bf(b.w);
  return p;
}

__device__ __forceinline__ bfrag cvt8(f32x4 lo, f32x4 hi) {
  bfrag r;
  r[0] = (__bf16)lo[0]; r[1] = (__bf16)lo[1];
  r[2] = (__bf16)lo[2]; r[3] = (__bf16)lo[3];
  r[4] = (__bf16)hi[0]; r[5] = (__bf16)hi[1];
  r[6] = (__bf16)hi[2]; r[7] = (__bf16)hi[3];
  return r;
}

__global__ void k_zero(int* __restrict__ cursor) {
  if (threadIdx.x < NEXP) cursor[threadIdx.x] = 0;
}

// Fused: blocks 0..63 scatter tokens by expert; blocks 64..1087 convert
// weight fp32 -> bf16 (contiguous [E][O][I]).
__global__ void k_prep(const int* __restrict__ gate, int* __restrict__ cursor,
                       int* __restrict__ perm, const float* __restrict__ w,
                       s8v* __restrict__ wb) {
  __shared__ int lc[NEXP], lb[NEXP];
  const int bid = blockIdx.x, tid = threadIdx.x;
  if (bid < 64) {
    if (tid < NEXP) lc[tid] = 0;
    __syncthreads();
    int t = bid * 256 + tid;
    int e = gate[t];
    int ls = atomicAdd(&lc[e], 1);
    __syncthreads();
    if (tid < NEXP) lb[tid] = lc[tid] ? atomicAdd(&cursor[tid], lc[tid]) : 0;
    __syncthreads();
    perm[e * EROWS + lb[e] + ls] = t;
  } else {
    int idx = (bid - 64) * 256 + tid;
    const float4* src = (const float4*)w + (size_t)idx * 2;
    wb[idx] = pack8(src[0], src[1]);
  }
}

// Grouped GEMM, nt-collapsed: one block = 32 tokens x FULL 512 outputs.
//  - A (32 fp32 token rows) read from global EXACTLY ONCE per row; staged via
//    one gload16/thread/step into 2-slot XOR-swizzled LDS (4KB/slot), shared
//    by all 4 waves. Swizzle both-sides (rule #21): src clog=c^(row&7),
//    read phys = l^(row&7) -> 2-way banks (free, m136).
//  - B (bf16 W_e) loaded DIRECT to registers; wave w owns cols w*128..+127
//    (disjoint -> W_e read once per block, XCD-L2-resident: e = bid&7 -> XCD e).
//  - Plain __syncthreads per step; no manual waitcnt anywhere.
__global__ __launch_bounds__(256, 2)
void moe_gemm6(const float* __restrict__ inp, const short* __restrict__ wbf,
               const int* __restrict__ cursor, const int* __restrict__ perm,
               float* __restrict__ out) {
  const int bid = blockIdx.x;
  const int e  = bid & 7;
  const int mt = bid >> 3;
  const int cnt = cursor[e];
  if (mt * BM >= cnt) return;
  const int m_valid = min(BM, cnt - mt * BM);
  const int* pb = perm + e * EROWS + mt * BM;

  __shared__ __align__(16) char Albs[2][BM * KS * 4];   // 2 x 4 KB
  __shared__ int toks[BM];

  const int tid = threadIdx.x;
  if (tid < BM) toks[tid] = pb[(tid < m_valid) ? tid : 0];
  __syncthreads();

  const int lane = tid & 63;
  const int wid  = tid >> 6;          // wave -> output cols [wid*128, wid*128+128)
  const int lr = lane & 15;
  const int lg = lane >> 4;

  // A DMA geometry: thread -> row = tid>>3, cphys = tid&7; fetch logical
  // chunk clog = cphys ^ (row&7); LDS dest linear at tid*16.
  const int arow = tid >> 3;
  const int acl  = (tid & 7) ^ (arow & 7);
  const float* agp = inp + (size_t)toks[arow] * INF + acl * 4;

  // B register-load addresses: rows wid*128 + j*16 + lr of W_e, k base lg*8.
  const short* wb0 = wbf + ((size_t)e * OUTF + (size_t)wid * 128) * INF;
  const short* baddr[8];
#pragma unroll
  for (int j = 0; j < 8; j++)
    baddr[j] = wb0 + (size_t)(j * 16 + lr) * INF + lg * 8;

  f32x4 acc[2][8];
#pragma unroll
  for (int m = 0; m < 2; m++)
#pragma unroll
    for (int j = 0; j < 8; j++) acc[m][j] = (f32x4)0.0f;

  bfrag Br[2][8];

  // ---- prologue: stage step 0 ----
  gload16(agp, (char*)Albs[0] + tid * 16);
#pragma unroll
  for (int j = 0; j < 8; j++) Br[0][j] = *(const bfrag*)(baddr[j]);
  __syncthreads();   // drains A(0) DMA + B(0) loads

#pragma unroll
  for (int t = 0; t < NST; t++) {     // fully unrolled -> all indices static
    const int cur = t & 1;
    if (t + 1 < NST) {                // prefetch next step (overlaps COMP)
      gload16(agp + (t + 1) * KS, (char*)Albs[cur ^ 1] + tid * 16);
#pragma unroll
      for (int j = 0; j < 8; j++)
        Br[cur ^ 1][j] = *(const bfrag*)(baddr[j] + (t + 1) * KS);
    }

    // ---- compute step t ----
    bfrag af[2];
#pragma unroll
    for (int m = 0; m < 2; m++) {
      int row = m * 16 + lr;
      int c0 = (lg * 2) ^ (row & 7);
      int c1 = (lg * 2 + 1) ^ (row & 7);
      f32x4 lo = *(const f32x4*)((const char*)Albs[cur] + row * 128 + c0 * 16);
      f32x4 hi = *(const f32x4*)((const char*)Albs[cur] + row * 128 + c1 * 16);
      af[m] = cvt8(lo, hi);
    }
#pragma unroll
    for (int m = 0; m < 2; m++)
#pragma unroll
      for (int j = 0; j < 8; j++)
        acc[m][j] = __builtin_amdgcn_mfma_f32_16x16x32_bf16(af[m], Br[cur][j],
                                                            acc[m][j], 0, 0, 0);
    __syncthreads();  // A(t+1) resident, B(t+1) regs landed, slot reuse safe
  }

  // ---- epilogue: C/D col=lane&15, row=(lane>>4)*4+reg (proven mapping) ----
#pragma unroll
  for (int m = 0; m < 2; m++) {
#pragma unroll
    for (int r = 0; r < 4; r++) {
      int rowE = m * 16 + lg * 4 + r;
      if (rowE < m_valid) {
        float* orow = out + (size_t)toks[rowE] * OUTF + (size_t)wid * 128 + lr;
#pragma unroll
        for (int j = 0; j < 8; j++) orow[j * 16] = acc[m][j][r];
      }
    }
  }
}

extern "C" void kernel_launch(void* const* d_in, const int* in_sizes, int n_in,
                              void* d_out, int out_size, void* d_ws, size_t ws_size,
                              hipStream_t stream) {
  (void)in_sizes; (void)n_in; (void)out_size; (void)ws_size;
  const float* inp    = (const float*)d_in[0];
  const int*   gate   = (const int*)d_in[1];
  const float* weight = (const float*)d_in[2];
  float* out = (float*)d_out;

  char* ws = (char*)d_ws;
  int*   cursor = (int*)ws;                    // 64 B
  int*   perm   = (int*)(ws + 4096);           // 8*2560*4 = 80 KB
  short* wbf    = (short*)(ws + (1 << 20));    // 4 MB bf16 weight

  k_zero<<<1, 64, 0, stream>>>(cursor);
  k_prep<<<64 + (NEXP * OUTF * INF) / (256 * 8), 256, 0, stream>>>(
      gate, cursor, perm, weight, (s8v*)wbf);
  moe_gemm6<<<NEXP * MAXMT, 256, 0, stream>>>(inp, wbf, cursor, perm, out);
}

// Round 11
// 35.050 us; speedup vs baseline: 1.9012x; 1.8520x over previous
//
#include <hip/hip_runtime.h>
#include <hip/hip_bf16.h>

#define TOKENS 16384
#define NEXP 8
#define INF 512
#define OUTF 512

#define BM 64
#define BN 128
#define BK 64
#define NST (INF / BK)     // 8 K-steps
#define MAXMT 40           // 2560 rows/expert; counts ~2048±42(σ) -> +12σ safe
#define EROWS (MAXMT * BM)

using f32x4 = __attribute__((ext_vector_type(4))) float;
using bfrag = __attribute__((ext_vector_type(8))) __bf16;
using s8v   = __attribute__((ext_vector_type(8))) short;

// fp32 -> bf16 RNE
__device__ __forceinline__ short f2bf(float f) {
  union { float f; unsigned u; } v; v.f = f;
  unsigned r = v.u + 0x7fffu + ((v.u >> 16) & 1u);
  return (short)(r >> 16);
}

__device__ __forceinline__ void gload16(const void* g, void* l) {
  __builtin_amdgcn_global_load_lds(
      (const __attribute__((address_space(1))) unsigned int*)g,
      (__attribute__((address_space(3))) unsigned int*)l, 16, 0, 0);
}

__device__ __forceinline__ s8v pack8(float4 a, float4 b) {
  s8v p;
  p[0] = f2bf(a.x); p[1] = f2bf(a.y); p[2] = f2bf(a.z); p[3] = f2bf(a.w);
  p[4] = f2bf(b.x); p[5] = f2bf(b.y); p[6] = f2bf(b.z); p[7] = f2bf(b.w);
  return p;
}

__device__ __forceinline__ bfrag cvt8(f32x4 lo, f32x4 hi) {
  bfrag r;
  r[0] = (__bf16)lo[0]; r[1] = (__bf16)lo[1];
  r[2] = (__bf16)lo[2]; r[3] = (__bf16)lo[3];
  r[4] = (__bf16)hi[0]; r[5] = (__bf16)hi[1];
  r[6] = (__bf16)hi[2]; r[7] = (__bf16)hi[3];
  return r;
}

__global__ void k_zero(int* __restrict__ cursor) {
  if (threadIdx.x < NEXP) cursor[threadIdx.x] = 0;
}

// Fused: blocks 0..63 scatter tokens by expert; blocks 64..1087 convert
// weight fp32 -> bf16 (contiguous [E][O][I]).
__global__ void k_prep(const int* __restrict__ gate, int* __restrict__ cursor,
                       int* __restrict__ perm, const float* __restrict__ w,
                       s8v* __restrict__ wb) {
  __shared__ int lc[NEXP], lb[NEXP];
  const int bid = blockIdx.x, tid = threadIdx.x;
  if (bid < 64) {
    if (tid < NEXP) lc[tid] = 0;
    __syncthreads();
    int t = bid * 256 + tid;
    int e = gate[t];
    int ls = atomicAdd(&lc[e], 1);
    __syncthreads();
    if (tid < NEXP) lb[tid] = lc[tid] ? atomicAdd(&cursor[tid], lc[tid]) : 0;
    __syncthreads();
    perm[e * EROWS + lb[e] + ls] = t;
  } else {
    int idx = (bid - 64) * 256 + tid;
    const float4* src = (const float4*)w + (size_t)idx * 2;
    wb[idx] = pack8(src[0], src[1]);
  }
}

// Grouped GEMM, occupancy-first geometry: 64x128 tile, ~1024 active blocks
// (4/CU, 16 waves/CU), 1-phase single-buffer, plain __syncthreads (no manual
// waitcnt). Cross-block overlap hides the per-step drain (m114).
// bid = e + 8*(nt + 4*mt): e -> XCD (B_e L2-hot); the 4 nt-siblings of one
// A-tile dispatch back-to-back on the SAME XCD -> A re-reads are L2 hits.
// A staged fp32 (cvt8 at fragment read, R8-proven); B bf16 (k_prep).
// Swizzles both-sides (rule #21): A clog=c^(row&15) [16 chunks/row];
// B clog=c^(row&7) [8 chunks/row] — R4-proven.
__global__ __launch_bounds__(256, 4)
void moe_gemm7(const float* __restrict__ inp, const short* __restrict__ wbf,
               const int* __restrict__ cursor, const int* __restrict__ perm,
               float* __restrict__ out) {
  const int bid = blockIdx.x;
  const int e  = bid & 7;
  const int nt = (bid >> 3) & 3;
  const int mt = bid >> 5;
  const int cnt = cursor[e];
  if (mt * BM >= cnt) return;
  const int m_valid = min(BM, cnt - mt * BM);
  const int* pb = perm + e * EROWS + mt * BM;

  __shared__ __align__(16) char Albs[BM * BK * 4];   // 16 KB fp32 A
  __shared__ __align__(16) char Blbs[BN * BK * 2];   // 16 KB bf16 B
  __shared__ int toks[BM];

  const int tid = threadIdx.x;
  if (tid < BM) toks[tid] = pb[(tid < m_valid) ? tid : 0];
  __syncthreads();

  const int lane = tid & 63;
  const int wid  = tid >> 6;
  const int wr = wid >> 1, wc = wid & 1;   // wave: rows wr*32..+31, cols wc*64..+63
  const int lr = lane & 15;
  const int lg = lane >> 4;

  // ---- A DMA geometry: 4 sites; chunk = s*256+tid -> row = s*16+(tid>>4),
  //      cphys = tid&15; source clog = cphys ^ (row&15); dest linear.
  const float* agp[4];
#pragma unroll
  for (int s = 0; s < 4; s++) {
    int row  = s * 16 + (tid >> 4);
    int clog = (tid & 15) ^ (row & 15);
    agp[s] = inp + (size_t)toks[row] * INF + clog * 4;
  }

  // ---- B DMA geometry: 4 sites; chunk = s*256+tid -> row = s*32+(tid>>3),
  //      cphys = tid&7; source clog = cphys ^ (row&7); dest linear.
  const short* Wbase = wbf + ((size_t)e * OUTF + (size_t)nt * BN) * INF;
  const short* bgp[4];
#pragma unroll
  for (int s = 0; s < 4; s++) {
    int row  = s * 32 + (tid >> 3);
    int clog = (tid & 7) ^ (row & 7);
    bgp[s] = Wbase + (size_t)row * INF + clog * 8;
  }

  f32x4 acc[2][4];
#pragma unroll
  for (int m = 0; m < 2; m++)
#pragma unroll
    for (int j = 0; j < 4; j++) acc[m][j] = (f32x4)0.0f;

  for (int t = 0; t < NST; t++) {
    // ---- stage tile t (8 homogeneous gload16/thread) ----
#pragma unroll
    for (int s = 0; s < 4; s++)
      gload16(agp[s] + t * BK, Albs + s * 4096 + tid * 16);
#pragma unroll
    for (int s = 0; s < 4; s++)
      gload16(bgp[s] + t * BK, Blbs + s * 4096 + tid * 16);
    __syncthreads();   // drain DMA

    // ---- compute (2 ks x 2 m x 4 n = 16 MFMA/wave) ----
#pragma unroll
    for (int ks = 0; ks < 2; ks++) {
      bfrag af[2], bv[4];
#pragma unroll
      for (int m = 0; m < 2; m++) {
        int row = wr * 32 + m * 16 + lr;
        int c0 = (ks * 8 + lg * 2) ^ (row & 15);
        int c1 = (ks * 8 + lg * 2 + 1) ^ (row & 15);
        f32x4 lo = *(const f32x4*)(Albs + row * 256 + c0 * 16);
        f32x4 hi = *(const f32x4*)(Albs + row * 256 + c1 * 16);
        af[m] = cvt8(lo, hi);
      }
#pragma unroll
      for (int j = 0; j < 4; j++) {
        int row = wc * 64 + j * 16 + lr;
        int c = (ks * 4 + lg) ^ (row & 7);
        bv[j] = *(const bfrag*)(Blbs + row * 128 + c * 16);
      }
#pragma unroll
      for (int m = 0; m < 2; m++)
#pragma unroll
        for (int j = 0; j < 4; j++)
          acc[m][j] = __builtin_amdgcn_mfma_f32_16x16x32_bf16(af[m], bv[j],
                                                              acc[m][j], 0, 0, 0);
    }
    if (t + 1 < NST) __syncthreads();  // reads done before next overwrite
  }

  // ---- epilogue: C/D col=lane&15, row=(lane>>4)*4+reg (proven) ----
#pragma unroll
  for (int m = 0; m < 2; m++) {
#pragma unroll
    for (int r = 0; r < 4; r++) {
      int rowE = wr * 32 + m * 16 + lg * 4 + r;
      if (rowE < m_valid) {
        float* orow = out + (size_t)toks[rowE] * OUTF + (size_t)nt * BN +
                      (size_t)wc * 64 + lr;
#pragma unroll
        for (int j = 0; j < 4; j++) orow[j * 16] = acc[m][j][r];
      }
    }
  }
}

extern "C" void kernel_launch(void* const* d_in, const int* in_sizes, int n_in,
                              void* d_out, int out_size, void* d_ws, size_t ws_size,
                              hipStream_t stream) {
  (void)in_sizes; (void)n_in; (void)out_size; (void)ws_size;
  const float* inp    = (const float*)d_in[0];
  const int*   gate   = (const int*)d_in[1];
  const float* weight = (const float*)d_in[2];
  float* out = (float*)d_out;

  char* ws = (char*)d_ws;
  int*   cursor = (int*)ws;                    // 64 B
  int*   perm   = (int*)(ws + 4096);           // 8*2560*4 = 80 KB
  short* wbf    = (short*)(ws + (1 << 20));    // 4 MB bf16 weight

  k_zero<<<1, 64, 0, stream>>>(cursor);
  k_prep<<<64 + (NEXP * OUTF * INF) / (256 * 8), 256, 0, stream>>>(
      gate, cursor, perm, weight, (s8v*)wbf);
  moe_gemm7<<<NEXP * 4 * MAXMT, 256, 0, stream>>>(inp, wbf, cursor, perm, out);
}